// Round 9
// baseline (502.198 us; speedup 1.0000x reference)
//
#include <hip/hip_runtime.h>

#define B 64
#define L 512
#define D 256
#define T 4096
#define LN_EPS 1e-5f

typedef __attribute__((ext_vector_type(8))) short bf16x8;
typedef __attribute__((ext_vector_type(4))) float f32x4;

__device__ __forceinline__ unsigned short f2bf(float f) {
    unsigned int u = __float_as_uint(f);
    unsigned int r = (u + 0x7FFFu + ((u >> 16) & 1u)) >> 16;  // RNE
    return (unsigned short)r;
}

// ---------------- prep: w->bf16 transpose (blocks 0..47) + cumsum (all 64 blocks) ----------------
__global__ __launch_bounds__(256) void prep_kernel(const float* __restrict__ w1,
                                                   const float* __restrict__ w2,
                                                   unsigned short* __restrict__ o1,
                                                   unsigned short* __restrict__ o2,
                                                   const int* __restrict__ target,
                                                   int* __restrict__ ends) {
    const int bid = blockIdx.x;  // 64 blocks
    const int tid = threadIdx.x;

    // --- per-batch inclusive cumsum (wave 0 of each block, batch = bid) ---
    if (tid < 64) {
        const int lane = tid;
        const int* trow = target + bid * L;
        int* erow = ends + bid * L;
        int vals[8];
        int base = lane * 8;
#pragma unroll
        for (int j = 0; j < 8; ++j) vals[j] = trow[base + j];
#pragma unroll
        for (int j = 1; j < 8; ++j) vals[j] += vals[j - 1];
        int lsum = vals[7];
        int s = lsum;
#pragma unroll
        for (int off = 1; off < 64; off <<= 1) {
            int v = __shfl_up(s, off, 64);
            if (lane >= off) s += v;
        }
        int excl = s - lsum;
#pragma unroll
        for (int j = 0; j < 8; ++j) erow[base + j] = excl + vals[j];
    }

    // --- weight convert+transpose: w[k][d][f] -> wT[k][f][d], blocks 0..47 ---
    if (bid < 48) {
        const int k = bid % 3;
        const int which = (bid / 3) & 1;
        const int d0 = (bid / 6) * 32;
        const float* in = which ? w2 : w1;
        unsigned short* out = which ? o2 : o1;
        const int f = tid;
        for (int dc = 0; dc < 32; dc += 8) {
            unsigned short v[8];
#pragma unroll
            for (int i = 0; i < 8; ++i) v[i] = f2bf(in[(k * 256 + d0 + dc + i) * 256 + f]);
            *(bf16x8*)(out + (k * 256 + f) * 256 + d0 + dc) = *(bf16x8*)v;
        }
    }
}

// ---------------- MFMA conv1d(k=3,256->256) + LN + ReLU [+ linear->dp], fused ----------------
// BM=32 rows/block -> grid (16,64)=1024 blocks (4/CU target). 4 waves: wave tile 16(M) x 128(N),
// acc = 8 frags (32 VGPR). Weight fragments explicitly double-buffered in registers so the
// L2 load latency of step ks+1 overlaps the 8 MFMAs of step ks.
template <bool IN_F32, bool FUSE_LINEAR>
__global__ __launch_bounds__(256, 3) void conv_fused_kernel(
    const void* __restrict__ xin,            // fp32 (B,512,256) if IN_F32 else bf16
    const unsigned short* __restrict__ wT,   // bf16 (3,256,256) [k][f][d]
    const float* __restrict__ bias, const float* __restrict__ g, const float* __restrict__ beta,
    const float* __restrict__ lin_w, const float* __restrict__ lin_b,
    unsigned short* __restrict__ hout,  // bf16 (B,512,256) out (conv1)
    float* __restrict__ dp)             // fp32 (B,512) out (conv2)
{
    constexpr int LS = 264;  // LDS row stride in bf16 elements (+8 pad)
    __shared__ __align__(16) unsigned short xs[34 * LS];
    __shared__ float psum[32][2];
    __shared__ float psq[32][2];
    __shared__ float muA[32], rsA[32];

    const int tid = threadIdx.x;
    const int lane = tid & 63;
    const int wid = tid >> 6;
    const int l15 = lane & 15;
    const int g4 = lane >> 4;
    const int b = blockIdx.y;
    const int l0 = blockIdx.x * 32;
    const int wr = wid >> 1;          // 0..1 -> rows wr*16 .. wr*16+15
    const int wn = (wid & 1) * 128;   // N half

    // ---- stage x rows l0-1 .. l0+32 into LDS (convert fp32->bf16 if IN_F32) ----
    for (int i = tid; i < 34 * 32; i += 256) {
        int r = i >> 5, c = i & 31;
        int grow = l0 - 1 + r;
        bf16x8 v = {0, 0, 0, 0, 0, 0, 0, 0};
        if (grow >= 0 && grow < L) {
            if constexpr (IN_F32) {
                const float* xr = (const float*)xin + ((size_t)(b * L + grow)) * D + c * 8;
                f32x4 f0 = *(const f32x4*)xr;
                f32x4 f1 = *(const f32x4*)(xr + 4);
                unsigned short t[8] = {f2bf(f0.x), f2bf(f0.y), f2bf(f0.z), f2bf(f0.w),
                                       f2bf(f1.x), f2bf(f1.y), f2bf(f1.z), f2bf(f1.w)};
                v = *(bf16x8*)t;
            } else {
                v = *(const bf16x8*)((const unsigned short*)xin + ((size_t)(b * L + grow)) * D + c * 8);
            }
        }
        *(bf16x8*)(xs + r * LS + c * 8) = v;
    }
    __syncthreads();

    f32x4 acc[8];
#pragma unroll
    for (int n = 0; n < 8; ++n) acc[n] = (f32x4){0.f, 0.f, 0.f, 0.f};

    const unsigned short* wbase = wT + (wn + l15) * 256 + g4 * 8;

    bf16x8 bcur[8];
#pragma unroll
    for (int n = 0; n < 8; ++n) bcur[n] = *(const bf16x8*)(wbase + n * 4096);

#pragma unroll 4
    for (int ks = 0; ks < 23; ++ks) {
        const int tap = ks >> 3, kk = ks & 7;
        bf16x8 a0 = *(const bf16x8*)(xs + (wr * 16 + l15 + tap) * LS + kk * 32 + g4 * 8);
        // prefetch weight fragments for ks+1 (overlaps the MFMAs below)
        const int ksn = ks + 1;
        const unsigned short* wp = wbase + (ksn >> 3) * 65536 + (ksn & 7) * 32;
        bf16x8 bnext[8];
#pragma unroll
        for (int n = 0; n < 8; ++n) bnext[n] = *(const bf16x8*)(wp + n * 4096);
#pragma unroll
        for (int n = 0; n < 8; ++n)
            acc[n] = __builtin_amdgcn_mfma_f32_16x16x32_bf16(a0, bcur[n], acc[n], 0, 0, 0);
#pragma unroll
        for (int n = 0; n < 8; ++n) bcur[n] = bnext[n];
    }
    {   // ks = 23
        bf16x8 a0 = *(const bf16x8*)(xs + (wr * 16 + l15 + 2) * LS + 7 * 32 + g4 * 8);
#pragma unroll
        for (int n = 0; n < 8; ++n)
            acc[n] = __builtin_amdgcn_mfma_f32_16x16x32_bf16(a0, bcur[n], acc[n], 0, 0, 0);
    }

    // ---- epilogue constants (per-lane cols: wn + n*16 + l15) ----
    float biasv[8], gv[8], bv[8], lwv[8];
#pragma unroll
    for (int n = 0; n < 8; ++n) {
        int col = wn + n * 16 + l15;
        biasv[n] = bias[col];
        gv[n] = g[col];
        bv[n] = beta[col];
        lwv[n] = FUSE_LINEAR ? lin_w[col] : 0.f;
    }

    // ---- LN stats: per-row sum/sumsq (row = wr*16 + g4*4 + j; C/D col=l15) ----
#pragma unroll
    for (int j = 0; j < 4; ++j) {
        float s = 0.f, q = 0.f;
#pragma unroll
        for (int n = 0; n < 8; ++n) {
            float v = acc[n][j] + biasv[n];
            s += v;
            q += v * v;
        }
#pragma unroll
        for (int off = 1; off < 16; off <<= 1) {
            s += __shfl_xor(s, off, 64);
            q += __shfl_xor(q, off, 64);
        }
        if (l15 == 0) {
            int row = wr * 16 + g4 * 4 + j;
            psum[row][wid & 1] = s;
            psq[row][wid & 1] = q;
        }
    }
    __syncthreads();
    if (tid < 32) {
        float s = psum[tid][0] + psum[tid][1];
        float q = psq[tid][0] + psq[tid][1];
        float mu = s * (1.f / 256.f);
        float var = q * (1.f / 256.f) - mu * mu;
        muA[tid] = mu;
        rsA[tid] = rsqrtf(var + LN_EPS);
    }
    __syncthreads();

    if constexpr (!FUSE_LINEAR) {
#pragma unroll
        for (int j = 0; j < 4; ++j) {
            int row = wr * 16 + g4 * 4 + j;
            float mu = muA[row], rs = rsA[row];
            size_t base = ((size_t)(b * L + l0 + row)) * D + wn + l15;
#pragma unroll
            for (int n = 0; n < 8; ++n) {
                float v = acc[n][j] + biasv[n];
                float y = fmaxf((v - mu) * rs * gv[n] + bv[n], 0.f);
                hout[base + n * 16] = f2bf(y);
            }
        }
    } else {
        float lb0 = lin_b[0];
#pragma unroll
        for (int j = 0; j < 4; ++j) {
            int row = wr * 16 + g4 * 4 + j;
            float mu = muA[row], rs = rsA[row];
            float p = 0.f;
#pragma unroll
            for (int n = 0; n < 8; ++n) {
                float v = acc[n][j] + biasv[n];
                float y = fmaxf((v - mu) * rs * gv[n] + bv[n], 0.f);
                p += y * lwv[n];
            }
#pragma unroll
            for (int off = 1; off < 16; off <<= 1) p += __shfl_xor(p, off, 64);
            if (l15 == 0) psum[row][wid & 1] = p;
        }
        __syncthreads();
        if (tid < 32) dp[b * L + l0 + tid] = fmaxf(psum[tid][0] + psum[tid][1] + lb0, 0.f);
    }
}

// ---------------- length regulate: ends in LDS, thread-parallel searches, NT float4 stores ----------------
__global__ __launch_bounds__(256) void length_regulate_kernel(
    const float* __restrict__ x, const int* __restrict__ ends, float* __restrict__ out) {
    __shared__ int se[512];
    __shared__ int sidx[256];
    const int tid = threadIdx.x;
    const int lane = tid & 63;
    const int wid = tid >> 6;
    const int b = blockIdx.y;
    const int t0 = blockIdx.x * 256;
    const int* e = ends + b * L;
    se[tid] = e[tid];
    se[tid + 256] = e[tid + 256];
    __syncthreads();
    const int total = se[511];
    {
        int t = t0 + tid;
        int lo = 0, hi = L;  // upper_bound in LDS
        while (lo < hi) {
            int mid = (lo + hi) >> 1;
            if (se[mid] <= t) lo = mid + 1; else hi = mid;
        }
        sidx[tid] = (lo < L - 1) ? lo : (L - 1);
    }
    __syncthreads();
    const f32x4* x4 = (const f32x4*)(x + (size_t)b * L * D);
    f32x4* o4 = (f32x4*)(out + (size_t)b * T * D);
    const f32x4 z = (f32x4){0.f, 0.f, 0.f, 0.f};
#pragma unroll 4
    for (int rr = 0; rr < 64; ++rr) {
        int row = wid * 64 + rr;
        int t = t0 + row;
        f32x4 v = z;
        if (t < total) v = x4[sidx[row] * 64 + lane];
        __builtin_nontemporal_store(v, &o4[(size_t)t * 64 + lane]);
    }
}

extern "C" void kernel_launch(void* const* d_in, const int* in_sizes, int n_in,
                              void* d_out, int out_size, void* d_ws, size_t ws_size,
                              hipStream_t stream) {
    const float* x   = (const float*)d_in[0];
    const int* target = (const int*)d_in[1];
    const float* c1w = (const float*)d_in[3];
    const float* c1b = (const float*)d_in[4];
    const float* g1  = (const float*)d_in[5];
    const float* b1  = (const float*)d_in[6];
    const float* c2w = (const float*)d_in[7];
    const float* c2b = (const float*)d_in[8];
    const float* g2  = (const float*)d_in[9];
    const float* b2  = (const float*)d_in[10];
    const float* lw  = (const float*)d_in[11];
    const float* lb  = (const float*)d_in[12];

    float* out = (float*)d_out;                    // (B,T,D)
    float* dp  = out + (size_t)B * T * D;          // (B,L)

    // Scratch inside d_out's (B,T,D) region, consumed before length_regulate
    // (the last kernel) overwrites it (stream-serialized):
    //   h1  @ 0      : 16,777,216 B (bf16 B*L*D)
    //   wT1 @ 32 MiB :    393,216 B ; wT2 follows
    char* base = (char*)d_out;
    unsigned short* h1  = (unsigned short*)(base);
    unsigned short* wT1 = (unsigned short*)(base + (32u << 20));
    unsigned short* wT2 = (unsigned short*)(base + (32u << 20) + 393216);
    int* ends = (int*)d_ws;  // B*L ints

    prep_kernel<<<dim3(64), dim3(256), 0, stream>>>(c1w, c2w, wT1, wT2, target, ends);
    conv_fused_kernel<true, false><<<dim3(L / 32, B), dim3(256), 0, stream>>>(
        x, wT1, c1b, g1, b1, nullptr, nullptr, h1, nullptr);
    conv_fused_kernel<false, true><<<dim3(L / 32, B), dim3(256), 0, stream>>>(
        h1, wT2, c2b, g2, b2, lw, lb, nullptr, dp);
    length_regulate_kernel<<<dim3(T / 256, B), dim3(256), 0, stream>>>(x, ends, out);
}

// Round 10
// 399.368 us; speedup vs baseline: 1.2575x; 1.2575x over previous
//
#include <hip/hip_runtime.h>

#define B 64
#define L 512
#define D 256
#define T 4096
#define LN_EPS 1e-5f

typedef __attribute__((ext_vector_type(8))) short bf16x8;
typedef __attribute__((ext_vector_type(4))) float f32x4;

__device__ __forceinline__ unsigned short f2bf(float f) {
    unsigned int u = __float_as_uint(f);
    unsigned int r = (u + 0x7FFFu + ((u >> 16) & 1u)) >> 16;  // RNE
    return (unsigned short)r;
}

// ---------------- prep: w->bf16 transpose (blocks 0..47) + cumsum (all 64 blocks) ----------------
__global__ __launch_bounds__(256) void prep_kernel(const float* __restrict__ w1,
                                                   const float* __restrict__ w2,
                                                   unsigned short* __restrict__ o1,
                                                   unsigned short* __restrict__ o2,
                                                   const int* __restrict__ target,
                                                   int* __restrict__ ends) {
    const int bid = blockIdx.x;
    const int tid = threadIdx.x;

    if (tid < 64) {  // per-batch inclusive cumsum, batch = bid
        const int lane = tid;
        const int* trow = target + bid * L;
        int* erow = ends + bid * L;
        int vals[8];
        int base = lane * 8;
#pragma unroll
        for (int j = 0; j < 8; ++j) vals[j] = trow[base + j];
#pragma unroll
        for (int j = 1; j < 8; ++j) vals[j] += vals[j - 1];
        int lsum = vals[7];
        int s = lsum;
#pragma unroll
        for (int off = 1; off < 64; off <<= 1) {
            int v = __shfl_up(s, off, 64);
            if (lane >= off) s += v;
        }
        int excl = s - lsum;
#pragma unroll
        for (int j = 0; j < 8; ++j) erow[base + j] = excl + vals[j];
    }

    if (bid < 48) {  // weight convert+transpose: w[k][d][f] -> wT[k][f][d]
        const int k = bid % 3;
        const int which = (bid / 3) & 1;
        const int d0 = (bid / 6) * 32;
        const float* in = which ? w2 : w1;
        unsigned short* out = which ? o2 : o1;
        const int f = tid;
        for (int dc = 0; dc < 32; dc += 8) {
            unsigned short v[8];
#pragma unroll
            for (int i = 0; i < 8; ++i) v[i] = f2bf(in[(k * 256 + d0 + dc + i) * 256 + f]);
            *(bf16x8*)(out + (k * 256 + f) * 256 + d0 + dc) = *(bf16x8*)v;
        }
    }
}

// ---------------- fully-fused duration predictor ----------------
// One block = 64 output rows of one batch. Phase 1: conv1+LN1+ReLU for 80 h-rows
// (l0-8 .. l0+71, incl. halo; h kept in LDS, never hits HBM). Phase 2: conv2+LN2+
// ReLU+linear -> dp. Wave layout 1M x 4N: wave w owns cols [w*64, w*64+64) (4 B-frags),
// iterates all M-tiles (5 in phase 1, 4 in phase 2). Weight frags reg-double-buffered.
__global__ __launch_bounds__(256, 2) void dp_fused_kernel(
    const float* __restrict__ x,             // fp32 (B,512,256)
    const unsigned short* __restrict__ wT1,  // bf16 (3,256,256) [k][f][d]
    const unsigned short* __restrict__ wT2,
    const float* __restrict__ c1b, const float* __restrict__ g1, const float* __restrict__ b1,
    const float* __restrict__ c2b, const float* __restrict__ g2, const float* __restrict__ b2,
    const float* __restrict__ lw, const float* __restrict__ lb,
    float* __restrict__ dp)                  // fp32 (B,512)
{
    constexpr int LS = 264;  // LDS row stride (bf16 elems), +8 pad -> ~2-way conflicts
    __shared__ __align__(16) unsigned short xs[82 * LS];  // phase1: x rows l0-9..l0+72; phase2: h rows (slots 0..79)
    __shared__ float ps[80][4], pq[80][4];
    __shared__ float muA[80], rsA[80];

    const int tid = threadIdx.x;
    const int lane = tid & 63;
    const int wid = tid >> 6;
    const int l15 = lane & 15;
    const int g4 = lane >> 4;
    const int b = blockIdx.y;
    const int l0 = blockIdx.x * 64;
    const int col0 = wid * 64;  // wave's col base

    // ---- stage x rows l0-9 .. l0+72 (fp32 -> bf16), zero outside [0,512) ----
    for (int i = tid; i < 82 * 32; i += 256) {
        int r = i >> 5, c = i & 31;
        int row = l0 - 9 + r;
        bf16x8 v = {0, 0, 0, 0, 0, 0, 0, 0};
        if (row >= 0 && row < L) {
            const float* xr = x + ((size_t)(b * L + row)) * D + c * 8;
            f32x4 f0 = *(const f32x4*)xr;
            f32x4 f1 = *(const f32x4*)(xr + 4);
            unsigned short t[8] = {f2bf(f0.x), f2bf(f0.y), f2bf(f0.z), f2bf(f0.w),
                                   f2bf(f1.x), f2bf(f1.y), f2bf(f1.z), f2bf(f1.w)};
            v = *(bf16x8*)t;
        }
        *(bf16x8*)(xs + r * LS + c * 8) = v;
    }
    __syncthreads();

    float gv[4], bv[4], biasv[4];
#pragma unroll
    for (int n = 0; n < 4; ++n) {
        int col = col0 + n * 16 + l15;
        biasv[n] = c1b[col];
        gv[n] = g1[col];
        bv[n] = b1[col];
    }

    // ================= PHASE 1: conv1 (80 h-rows x 64 cols per wave) =================
    {
        f32x4 acc[5][4];
#pragma unroll
        for (int m = 0; m < 5; ++m)
#pragma unroll
            for (int n = 0; n < 4; ++n) acc[m][n] = (f32x4){0.f, 0.f, 0.f, 0.f};

        const unsigned short* wbase = wT1 + (col0 + l15) * 256 + g4 * 8;
        bf16x8 bcur[4];
#pragma unroll
        for (int n = 0; n < 4; ++n) bcur[n] = *(const bf16x8*)(wbase + n * 4096);

#pragma unroll 4
        for (int ks = 0; ks < 23; ++ks) {
            const int tap = ks >> 3, kk = ks & 7;
            const int ksn = ks + 1;
            const unsigned short* wp = wbase + (ksn >> 3) * 65536 + (ksn & 7) * 32;
            bf16x8 bnext[4];
#pragma unroll
            for (int n = 0; n < 4; ++n) bnext[n] = *(const bf16x8*)(wp + n * 4096);
            bf16x8 a[5];
#pragma unroll
            for (int m = 0; m < 5; ++m)
                a[m] = *(const bf16x8*)(xs + (m * 16 + l15 + tap) * LS + kk * 32 + g4 * 8);
#pragma unroll
            for (int m = 0; m < 5; ++m)
#pragma unroll
                for (int n = 0; n < 4; ++n)
                    acc[m][n] = __builtin_amdgcn_mfma_f32_16x16x32_bf16(a[m], bcur[n], acc[m][n], 0, 0, 0);
#pragma unroll
            for (int n = 0; n < 4; ++n) bcur[n] = bnext[n];
        }
        {  // ks = 23
            bf16x8 a[5];
#pragma unroll
            for (int m = 0; m < 5; ++m)
                a[m] = *(const bf16x8*)(xs + (m * 16 + l15 + 2) * LS + 7 * 32 + g4 * 8);
#pragma unroll
            for (int m = 0; m < 5; ++m)
#pragma unroll
                for (int n = 0; n < 4; ++n)
                    acc[m][n] = __builtin_amdgcn_mfma_f32_16x16x32_bf16(a[m], bcur[n], acc[m][n], 0, 0, 0);
        }

        // ---- LN1 stats (row = m*16 + g4*4 + j; cols: this wave's 64) ----
#pragma unroll
        for (int m = 0; m < 5; ++m)
#pragma unroll
            for (int j = 0; j < 4; ++j) {
                float s = 0.f, q = 0.f;
#pragma unroll
                for (int n = 0; n < 4; ++n) {
                    float v = acc[m][n][j] + biasv[n];
                    s += v;
                    q += v * v;
                }
#pragma unroll
                for (int off = 1; off < 16; off <<= 1) {
                    s += __shfl_xor(s, off, 64);
                    q += __shfl_xor(q, off, 64);
                }
                if (l15 == 0) {
                    int row = m * 16 + g4 * 4 + j;
                    ps[row][wid] = s;
                    pq[row][wid] = q;
                }
            }
        __syncthreads();
        if (tid < 80) {
            float s = ps[tid][0] + ps[tid][1] + ps[tid][2] + ps[tid][3];
            float q = pq[tid][0] + pq[tid][1] + pq[tid][2] + pq[tid][3];
            float mu = s * (1.f / 256.f);
            float var = q * (1.f / 256.f) - mu * mu;
            muA[tid] = mu;
            rsA[tid] = rsqrtf(var + LN_EPS);
        }
        __syncthreads();

        // ---- h = relu(LN(conv1)) -> back into xs (x is dead); zero pad rows ----
#pragma unroll
        for (int m = 0; m < 5; ++m)
#pragma unroll
            for (int j = 0; j < 4; ++j) {
                int srow = m * 16 + g4 * 4 + j;
                int hrow = l0 - 8 + srow;
                float mu = muA[srow], rs = rsA[srow];
                bool live = (hrow >= 0) && (hrow < L);
#pragma unroll
                for (int n = 0; n < 4; ++n) {
                    float v = acc[m][n][j] + biasv[n];
                    float y = fmaxf((v - mu) * rs * gv[n] + bv[n], 0.f);
                    if (!live) y = 0.f;
                    xs[srow * LS + col0 + n * 16 + l15] = f2bf(y);
                }
            }
    }
    __syncthreads();

    // ================= PHASE 2: conv2 + LN2 + ReLU + linear =================
    {
        float lwv[4];
#pragma unroll
        for (int n = 0; n < 4; ++n) {
            int col = col0 + n * 16 + l15;
            biasv[n] = c2b[col];
            gv[n] = g2[col];
            bv[n] = b2[col];
            lwv[n] = lw[col];
        }

        f32x4 acc[4][4];
#pragma unroll
        for (int m = 0; m < 4; ++m)
#pragma unroll
            for (int n = 0; n < 4; ++n) acc[m][n] = (f32x4){0.f, 0.f, 0.f, 0.f};

        const unsigned short* wbase = wT2 + (col0 + l15) * 256 + g4 * 8;
        bf16x8 bcur[4];
#pragma unroll
        for (int n = 0; n < 4; ++n) bcur[n] = *(const bf16x8*)(wbase + n * 4096);

#pragma unroll 4
        for (int ks = 0; ks < 23; ++ks) {
            const int tap = ks >> 3, kk = ks & 7;
            const int ksn = ks + 1;
            const unsigned short* wp = wbase + (ksn >> 3) * 65536 + (ksn & 7) * 32;
            bf16x8 bnext[4];
#pragma unroll
            for (int n = 0; n < 4; ++n) bnext[n] = *(const bf16x8*)(wp + n * 4096);
            bf16x8 a[4];
#pragma unroll
            for (int m = 0; m < 4; ++m)
                a[m] = *(const bf16x8*)(xs + (m * 16 + l15 + tap + 7) * LS + kk * 32 + g4 * 8);
#pragma unroll
            for (int m = 0; m < 4; ++m)
#pragma unroll
                for (int n = 0; n < 4; ++n)
                    acc[m][n] = __builtin_amdgcn_mfma_f32_16x16x32_bf16(a[m], bcur[n], acc[m][n], 0, 0, 0);
#pragma unroll
            for (int n = 0; n < 4; ++n) bcur[n] = bnext[n];
        }
        {  // ks = 23
            bf16x8 a[4];
#pragma unroll
            for (int m = 0; m < 4; ++m)
                a[m] = *(const bf16x8*)(xs + (m * 16 + l15 + 2 + 7) * LS + 7 * 32 + g4 * 8);
#pragma unroll
            for (int m = 0; m < 4; ++m)
#pragma unroll
                for (int n = 0; n < 4; ++n)
                    acc[m][n] = __builtin_amdgcn_mfma_f32_16x16x32_bf16(a[m], bcur[n], acc[m][n], 0, 0, 0);
        }

        // ---- LN2 stats ----
#pragma unroll
        for (int m = 0; m < 4; ++m)
#pragma unroll
            for (int j = 0; j < 4; ++j) {
                float s = 0.f, q = 0.f;
#pragma unroll
                for (int n = 0; n < 4; ++n) {
                    float v = acc[m][n][j] + biasv[n];
                    s += v;
                    q += v * v;
                }
#pragma unroll
                for (int off = 1; off < 16; off <<= 1) {
                    s += __shfl_xor(s, off, 64);
                    q += __shfl_xor(q, off, 64);
                }
                if (l15 == 0) {
                    int row = m * 16 + g4 * 4 + j;
                    ps[row][wid] = s;
                    pq[row][wid] = q;
                }
            }
        __syncthreads();
        if (tid < 64) {
            float s = ps[tid][0] + ps[tid][1] + ps[tid][2] + ps[tid][3];
            float q = pq[tid][0] + pq[tid][1] + pq[tid][2] + pq[tid][3];
            float mu = s * (1.f / 256.f);
            float var = q * (1.f / 256.f) - mu * mu;
            muA[tid] = mu;
            rsA[tid] = rsqrtf(var + LN_EPS);
        }
        __syncthreads();

        // ---- y = relu(LN2(conv2)); p = y . lw ; reduce -> dp ----
#pragma unroll
        for (int m = 0; m < 4; ++m)
#pragma unroll
            for (int j = 0; j < 4; ++j) {
                int row = m * 16 + g4 * 4 + j;
                float mu = muA[row], rs = rsA[row];
                float p = 0.f;
#pragma unroll
                for (int n = 0; n < 4; ++n) {
                    float v = acc[m][n][j] + biasv[n];
                    float y = fmaxf((v - mu) * rs * gv[n] + bv[n], 0.f);
                    p += y * lwv[n];
                }
#pragma unroll
                for (int off = 1; off < 16; off <<= 1) p += __shfl_xor(p, off, 64);
                if (l15 == 0) ps[row][wid] = p;
            }
        __syncthreads();
        if (tid < 64)
            dp[b * L + l0 + tid] = fmaxf(ps[tid][0] + ps[tid][1] + ps[tid][2] + ps[tid][3] + lb[0], 0.f);
    }
}

// ---------------- length regulate: ends in LDS, thread-parallel searches, float4 copy ----------------
__global__ __launch_bounds__(256) void length_regulate_kernel(
    const float* __restrict__ x, const int* __restrict__ ends, float* __restrict__ out) {
    __shared__ int se[512];
    __shared__ int sidx[256];
    const int tid = threadIdx.x;
    const int lane = tid & 63;
    const int wid = tid >> 6;
    const int b = blockIdx.y;
    const int t0 = blockIdx.x * 256;
    const int* e = ends + b * L;
    se[tid] = e[tid];
    se[tid + 256] = e[tid + 256];
    __syncthreads();
    const int total = se[511];
    {
        int t = t0 + tid;
        int lo = 0, hi = L;  // upper_bound in LDS
        while (lo < hi) {
            int mid = (lo + hi) >> 1;
            if (se[mid] <= t) lo = mid + 1; else hi = mid;
        }
        sidx[tid] = (lo < L - 1) ? lo : (L - 1);
    }
    __syncthreads();
    const f32x4* x4 = (const f32x4*)(x + (size_t)b * L * D);
    f32x4* o4 = (f32x4*)(out + (size_t)b * T * D);
    const f32x4 z = (f32x4){0.f, 0.f, 0.f, 0.f};
#pragma unroll 4
    for (int rr = 0; rr < 64; ++rr) {
        int row = wid * 64 + rr;
        int t = t0 + row;
        f32x4 v = z;
        if (t < total) v = x4[sidx[row] * 64 + lane];
        o4[(size_t)t * 64 + lane] = v;
    }
}

extern "C" void kernel_launch(void* const* d_in, const int* in_sizes, int n_in,
                              void* d_out, int out_size, void* d_ws, size_t ws_size,
                              hipStream_t stream) {
    const float* x   = (const float*)d_in[0];
    const int* target = (const int*)d_in[1];
    const float* c1w = (const float*)d_in[3];
    const float* c1b = (const float*)d_in[4];
    const float* g1  = (const float*)d_in[5];
    const float* b1  = (const float*)d_in[6];
    const float* c2w = (const float*)d_in[7];
    const float* c2b = (const float*)d_in[8];
    const float* g2  = (const float*)d_in[9];
    const float* b2  = (const float*)d_in[10];
    const float* lw  = (const float*)d_in[11];
    const float* lb  = (const float*)d_in[12];

    float* out = (float*)d_out;                    // (B,T,D)
    float* dp  = out + (size_t)B * T * D;          // (B,L)

    // Scratch (weights only now) inside d_out's big region, consumed before
    // length_regulate overwrites it (stream-serialized).
    char* base = (char*)d_out;
    unsigned short* wT1 = (unsigned short*)(base + (32u << 20));
    unsigned short* wT2 = (unsigned short*)(base + (32u << 20) + 393216);
    int* ends = (int*)d_ws;  // B*L ints

    prep_kernel<<<dim3(64), dim3(256), 0, stream>>>(c1w, c2w, wT1, wT2, target, ends);
    dp_fused_kernel<<<dim3(L / 64, B), dim3(256), 0, stream>>>(
        x, wT1, wT2, c1b, g1, b1, c2b, g2, b2, lw, lb, dp);
    length_regulate_kernel<<<dim3(T / 256, B), dim3(256), 0, stream>>>(x, ends, out);
}

// Round 11
// 383.725 us; speedup vs baseline: 1.3087x; 1.0408x over previous
//
#include <hip/hip_runtime.h>

#define B 64
#define L 512
#define D 256
#define T 4096
#define LN_EPS 1e-5f

typedef __attribute__((ext_vector_type(8))) short bf16x8;
typedef __attribute__((ext_vector_type(4))) float f32x4;

__device__ __forceinline__ unsigned short f2bf(float f) {
    unsigned int u = __float_as_uint(f);
    unsigned int r = (u + 0x7FFFu + ((u >> 16) & 1u)) >> 16;  // RNE
    return (unsigned short)r;
}

// ---------------- prep: w->bf16 transpose (blocks 0..47) + cumsum (all 64 blocks) ----------------
__global__ __launch_bounds__(256) void prep_kernel(const float* __restrict__ w1,
                                                   const float* __restrict__ w2,
                                                   unsigned short* __restrict__ o1,
                                                   unsigned short* __restrict__ o2,
                                                   const int* __restrict__ target,
                                                   int* __restrict__ ends) {
    const int bid = blockIdx.x;
    const int tid = threadIdx.x;

    if (tid < 64) {  // per-batch inclusive cumsum, batch = bid
        const int lane = tid;
        const int* trow = target + bid * L;
        int* erow = ends + bid * L;
        int vals[8];
        int base = lane * 8;
#pragma unroll
        for (int j = 0; j < 8; ++j) vals[j] = trow[base + j];
#pragma unroll
        for (int j = 1; j < 8; ++j) vals[j] += vals[j - 1];
        int lsum = vals[7];
        int s = lsum;
#pragma unroll
        for (int off = 1; off < 64; off <<= 1) {
            int v = __shfl_up(s, off, 64);
            if (lane >= off) s += v;
        }
        int excl = s - lsum;
#pragma unroll
        for (int j = 0; j < 8; ++j) erow[base + j] = excl + vals[j];
    }

    if (bid < 48) {  // weight convert+transpose: w[k][d][f] -> wT[k][f][d]
        const int k = bid % 3;
        const int which = (bid / 3) & 1;
        const int d0 = (bid / 6) * 32;
        const float* in = which ? w2 : w1;
        unsigned short* out = which ? o2 : o1;
        const int f = tid;
        for (int dc = 0; dc < 32; dc += 8) {
            unsigned short v[8];
#pragma unroll
            for (int i = 0; i < 8; ++i) v[i] = f2bf(in[(k * 256 + d0 + dc + i) * 256 + f]);
            *(bf16x8*)(out + (k * 256 + f) * 256 + d0 + dc) = *(bf16x8*)v;
        }
    }
}

// ---------------- mega kernel: dp blocks (0..511) + LR blocks (512..1535) ----------------
// dp block: fully-fused conv1+LN1+ReLU -> LDS -> conv2+LN2+ReLU+linear -> dp[b,l].
// LR block: 256 t-rows, LDS binary search + float4 row gather/store.
// Disjoint outputs; wT/ends live in d_ws so LR's d_out writes can't race dp's reads.
union SMem {
    struct {
        unsigned short xs[82 * 264];
        float ps[80][4], pq[80][4];
        float muA[80], rsA[80];
    } dp;
    struct {
        int se[512];
        int sidx[256];
    } lr;
};

__global__ __launch_bounds__(256, 2) void mega_kernel(
    const float* __restrict__ x,             // fp32 (B,512,256)
    const unsigned short* __restrict__ wT1,  // bf16 (3,256,256) [k][f][d]
    const unsigned short* __restrict__ wT2,
    const float* __restrict__ c1b, const float* __restrict__ g1, const float* __restrict__ b1,
    const float* __restrict__ c2b, const float* __restrict__ g2, const float* __restrict__ b2,
    const float* __restrict__ lw, const float* __restrict__ lb,
    const int* __restrict__ ends,
    float* __restrict__ out,                 // fp32 (B,T,D)
    float* __restrict__ dp)                  // fp32 (B,512)
{
    __shared__ SMem sm;
    const int tid = threadIdx.x;

    if (blockIdx.x >= 512) {
        // ================= LR block =================
        const int idx = blockIdx.x - 512;
        const int lane = tid & 63;
        const int wid = tid >> 6;
        const int b = idx >> 4;
        const int t0 = (idx & 15) * 256;
        const int* e = ends + b * L;
        sm.lr.se[tid] = e[tid];
        sm.lr.se[tid + 256] = e[tid + 256];
        __syncthreads();
        const int total = sm.lr.se[511];
        {
            int t = t0 + tid;
            int lo = 0, hi = L;  // upper_bound in LDS
            while (lo < hi) {
                int mid = (lo + hi) >> 1;
                if (sm.lr.se[mid] <= t) lo = mid + 1; else hi = mid;
            }
            sm.lr.sidx[tid] = (lo < L - 1) ? lo : (L - 1);
        }
        __syncthreads();
        const f32x4* x4 = (const f32x4*)(x + (size_t)b * L * D);
        f32x4* o4 = (f32x4*)(out + (size_t)b * T * D);
        const f32x4 z = (f32x4){0.f, 0.f, 0.f, 0.f};
#pragma unroll
        for (int rc = 0; rc < 8; ++rc) {  // 8 chunks of 8 rows: 8 loads in flight, then 8 stores
            f32x4 v[8];
#pragma unroll
            for (int u = 0; u < 8; ++u) {
                int row = wid * 64 + rc * 8 + u;
                int t = t0 + row;
                v[u] = (t < total) ? x4[sm.lr.sidx[row] * 64 + lane] : z;
            }
#pragma unroll
            for (int u = 0; u < 8; ++u) {
                int row = wid * 64 + rc * 8 + u;
                o4[(size_t)(t0 + row) * 64 + lane] = v[u];
            }
        }
        return;
    }

    // ================= dp block (identical numerics to R10's dp_fused) =================
    constexpr int LS = 264;
    const int lane = tid & 63;
    const int wid = tid >> 6;
    const int l15 = lane & 15;
    const int g4 = lane >> 4;
    const int b = blockIdx.x >> 3;
    const int l0 = (blockIdx.x & 7) * 64;
    const int col0 = wid * 64;

    unsigned short* xs = sm.dp.xs;

    // ---- stage x rows l0-9 .. l0+72 (fp32 -> bf16), zero outside [0,512) ----
    for (int i = tid; i < 82 * 32; i += 256) {
        int r = i >> 5, c = i & 31;
        int row = l0 - 9 + r;
        bf16x8 v = {0, 0, 0, 0, 0, 0, 0, 0};
        if (row >= 0 && row < L) {
            const float* xr = x + ((size_t)(b * L + row)) * D + c * 8;
            f32x4 f0 = *(const f32x4*)xr;
            f32x4 f1 = *(const f32x4*)(xr + 4);
            unsigned short t[8] = {f2bf(f0.x), f2bf(f0.y), f2bf(f0.z), f2bf(f0.w),
                                   f2bf(f1.x), f2bf(f1.y), f2bf(f1.z), f2bf(f1.w)};
            v = *(bf16x8*)t;
        }
        *(bf16x8*)(xs + r * LS + c * 8) = v;
    }
    __syncthreads();

    float gv[4], bv[4], biasv[4];
#pragma unroll
    for (int n = 0; n < 4; ++n) {
        int col = col0 + n * 16 + l15;
        biasv[n] = c1b[col];
        gv[n] = g1[col];
        bv[n] = b1[col];
    }

    // ---- PHASE 1: conv1 (80 h-rows x 64 cols per wave) ----
    {
        f32x4 acc[5][4];
#pragma unroll
        for (int m = 0; m < 5; ++m)
#pragma unroll
            for (int n = 0; n < 4; ++n) acc[m][n] = (f32x4){0.f, 0.f, 0.f, 0.f};

        const unsigned short* wbase = wT1 + (col0 + l15) * 256 + g4 * 8;
        bf16x8 bcur[4];
#pragma unroll
        for (int n = 0; n < 4; ++n) bcur[n] = *(const bf16x8*)(wbase + n * 4096);

#pragma unroll 4
        for (int ks = 0; ks < 23; ++ks) {
            const int tap = ks >> 3, kk = ks & 7;
            const int ksn = ks + 1;
            const unsigned short* wp = wbase + (ksn >> 3) * 65536 + (ksn & 7) * 32;
            bf16x8 bnext[4];
#pragma unroll
            for (int n = 0; n < 4; ++n) bnext[n] = *(const bf16x8*)(wp + n * 4096);
            bf16x8 a[5];
#pragma unroll
            for (int m = 0; m < 5; ++m)
                a[m] = *(const bf16x8*)(xs + (m * 16 + l15 + tap) * LS + kk * 32 + g4 * 8);
#pragma unroll
            for (int m = 0; m < 5; ++m)
#pragma unroll
                for (int n = 0; n < 4; ++n)
                    acc[m][n] = __builtin_amdgcn_mfma_f32_16x16x32_bf16(a[m], bcur[n], acc[m][n], 0, 0, 0);
#pragma unroll
            for (int n = 0; n < 4; ++n) bcur[n] = bnext[n];
        }
        {  // ks = 23
            bf16x8 a[5];
#pragma unroll
            for (int m = 0; m < 5; ++m)
                a[m] = *(const bf16x8*)(xs + (m * 16 + l15 + 2) * LS + 7 * 32 + g4 * 8);
#pragma unroll
            for (int m = 0; m < 5; ++m)
#pragma unroll
                for (int n = 0; n < 4; ++n)
                    acc[m][n] = __builtin_amdgcn_mfma_f32_16x16x32_bf16(a[m], bcur[n], acc[m][n], 0, 0, 0);
        }

#pragma unroll
        for (int m = 0; m < 5; ++m)
#pragma unroll
            for (int j = 0; j < 4; ++j) {
                float s = 0.f, q = 0.f;
#pragma unroll
                for (int n = 0; n < 4; ++n) {
                    float v = acc[m][n][j] + biasv[n];
                    s += v;
                    q += v * v;
                }
#pragma unroll
                for (int off = 1; off < 16; off <<= 1) {
                    s += __shfl_xor(s, off, 64);
                    q += __shfl_xor(q, off, 64);
                }
                if (l15 == 0) {
                    int row = m * 16 + g4 * 4 + j;
                    sm.dp.ps[row][wid] = s;
                    sm.dp.pq[row][wid] = q;
                }
            }
        __syncthreads();
        if (tid < 80) {
            float s = sm.dp.ps[tid][0] + sm.dp.ps[tid][1] + sm.dp.ps[tid][2] + sm.dp.ps[tid][3];
            float q = sm.dp.pq[tid][0] + sm.dp.pq[tid][1] + sm.dp.pq[tid][2] + sm.dp.pq[tid][3];
            float mu = s * (1.f / 256.f);
            float var = q * (1.f / 256.f) - mu * mu;
            sm.dp.muA[tid] = mu;
            sm.dp.rsA[tid] = rsqrtf(var + LN_EPS);
        }
        __syncthreads();

        // h = relu(LN(conv1)) -> back into xs; zero rows outside [0,L)
#pragma unroll
        for (int m = 0; m < 5; ++m)
#pragma unroll
            for (int j = 0; j < 4; ++j) {
                int srow = m * 16 + g4 * 4 + j;
                int hrow = l0 - 8 + srow;
                float mu = sm.dp.muA[srow], rs = sm.dp.rsA[srow];
                bool live = (hrow >= 0) && (hrow < L);
#pragma unroll
                for (int n = 0; n < 4; ++n) {
                    float v = acc[m][n][j] + biasv[n];
                    float y = fmaxf((v - mu) * rs * gv[n] + bv[n], 0.f);
                    if (!live) y = 0.f;
                    xs[srow * LS + col0 + n * 16 + l15] = f2bf(y);
                }
            }
    }
    __syncthreads();

    // ---- PHASE 2: conv2 + LN2 + ReLU + linear ----
    {
        float lwv[4];
#pragma unroll
        for (int n = 0; n < 4; ++n) {
            int col = col0 + n * 16 + l15;
            biasv[n] = c2b[col];
            gv[n] = g2[col];
            bv[n] = b2[col];
            lwv[n] = lw[col];
        }

        f32x4 acc[4][4];
#pragma unroll
        for (int m = 0; m < 4; ++m)
#pragma unroll
            for (int n = 0; n < 4; ++n) acc[m][n] = (f32x4){0.f, 0.f, 0.f, 0.f};

        const unsigned short* wbase = wT2 + (col0 + l15) * 256 + g4 * 8;
        bf16x8 bcur[4];
#pragma unroll
        for (int n = 0; n < 4; ++n) bcur[n] = *(const bf16x8*)(wbase + n * 4096);

#pragma unroll 4
        for (int ks = 0; ks < 23; ++ks) {
            const int tap = ks >> 3, kk = ks & 7;
            const int ksn = ks + 1;
            const unsigned short* wp = wbase + (ksn >> 3) * 65536 + (ksn & 7) * 32;
            bf16x8 bnext[4];
#pragma unroll
            for (int n = 0; n < 4; ++n) bnext[n] = *(const bf16x8*)(wp + n * 4096);
            bf16x8 a[4];
#pragma unroll
            for (int m = 0; m < 4; ++m)
                a[m] = *(const bf16x8*)(xs + (m * 16 + l15 + tap + 7) * LS + kk * 32 + g4 * 8);
#pragma unroll
            for (int m = 0; m < 4; ++m)
#pragma unroll
                for (int n = 0; n < 4; ++n)
                    acc[m][n] = __builtin_amdgcn_mfma_f32_16x16x32_bf16(a[m], bcur[n], acc[m][n], 0, 0, 0);
#pragma unroll
            for (int n = 0; n < 4; ++n) bcur[n] = bnext[n];
        }
        {  // ks = 23
            bf16x8 a[4];
#pragma unroll
            for (int m = 0; m < 4; ++m)
                a[m] = *(const bf16x8*)(xs + (m * 16 + l15 + 2 + 7) * LS + 7 * 32 + g4 * 8);
#pragma unroll
            for (int m = 0; m < 4; ++m)
#pragma unroll
                for (int n = 0; n < 4; ++n)
                    acc[m][n] = __builtin_amdgcn_mfma_f32_16x16x32_bf16(a[m], bcur[n], acc[m][n], 0, 0, 0);
        }

#pragma unroll
        for (int m = 0; m < 4; ++m)
#pragma unroll
            for (int j = 0; j < 4; ++j) {
                float s = 0.f, q = 0.f;
#pragma unroll
                for (int n = 0; n < 4; ++n) {
                    float v = acc[m][n][j] + biasv[n];
                    s += v;
                    q += v * v;
                }
#pragma unroll
                for (int off = 1; off < 16; off <<= 1) {
                    s += __shfl_xor(s, off, 64);
                    q += __shfl_xor(q, off, 64);
                }
                if (l15 == 0) {
                    int row = m * 16 + g4 * 4 + j;
                    sm.dp.ps[row][wid] = s;
                    sm.dp.pq[row][wid] = q;
                }
            }
        __syncthreads();
        if (tid < 64) {
            float s = sm.dp.ps[tid][0] + sm.dp.ps[tid][1] + sm.dp.ps[tid][2] + sm.dp.ps[tid][3];
            float q = sm.dp.pq[tid][0] + sm.dp.pq[tid][1] + sm.dp.pq[tid][2] + sm.dp.pq[tid][3];
            float mu = s * (1.f / 256.f);
            float var = q * (1.f / 256.f) - mu * mu;
            sm.dp.muA[tid] = mu;
            sm.dp.rsA[tid] = rsqrtf(var + LN_EPS);
        }
        __syncthreads();

#pragma unroll
        for (int m = 0; m < 4; ++m)
#pragma unroll
            for (int j = 0; j < 4; ++j) {
                int row = m * 16 + g4 * 4 + j;
                float mu = sm.dp.muA[row], rs = sm.dp.rsA[row];
                float p = 0.f;
#pragma unroll
                for (int n = 0; n < 4; ++n) {
                    float v = acc[m][n][j] + biasv[n];
                    float y = fmaxf((v - mu) * rs * gv[n] + bv[n], 0.f);
                    p += y * lwv[n];
                }
#pragma unroll
                for (int off = 1; off < 16; off <<= 1) p += __shfl_xor(p, off, 64);
                if (l15 == 0) sm.dp.ps[row][wid] = p;
            }
        __syncthreads();
        if (tid < 64)
            dp[b * L + l0 + tid] =
                fmaxf(sm.dp.ps[tid][0] + sm.dp.ps[tid][1] + sm.dp.ps[tid][2] + sm.dp.ps[tid][3] + lb[0], 0.f);
    }
}

extern "C" void kernel_launch(void* const* d_in, const int* in_sizes, int n_in,
                              void* d_out, int out_size, void* d_ws, size_t ws_size,
                              hipStream_t stream) {
    const float* x   = (const float*)d_in[0];
    const int* target = (const int*)d_in[1];
    const float* c1w = (const float*)d_in[3];
    const float* c1b = (const float*)d_in[4];
    const float* g1  = (const float*)d_in[5];
    const float* b1  = (const float*)d_in[6];
    const float* c2w = (const float*)d_in[7];
    const float* c2b = (const float*)d_in[8];
    const float* g2  = (const float*)d_in[9];
    const float* b2  = (const float*)d_in[10];
    const float* lw  = (const float*)d_in[11];
    const float* lb  = (const float*)d_in[12];

    float* out = (float*)d_out;                    // (B,T,D)
    float* dp  = out + (size_t)B * T * D;          // (B,L)

    // Scratch now entirely in d_ws (LR writes d_out concurrently with dp reads):
    //   ends @ 0        : 131,072 B
    //   wT1  @ 131072   : 393,216 B
    //   wT2  @ 524288   : 393,216 B   (total ~918 KB)
    char* wsb = (char*)d_ws;
    int* ends = (int*)wsb;
    unsigned short* wT1 = (unsigned short*)(wsb + 131072);
    unsigned short* wT2 = (unsigned short*)(wsb + 131072 + 393216);

    prep_kernel<<<dim3(64), dim3(256), 0, stream>>>(c1w, c2w, wT1, wT2, target, ends);
    mega_kernel<<<dim3(512 + 1024), dim3(256), 0, stream>>>(
        x, wT1, wT2, c1b, g1, b1, c2b, g2, b2, lw, lb, ends, out, dp);
}